// Round 1
// baseline (112.237 us; speedup 1.0000x reference)
//
#include <hip/hip_runtime.h>
#include <math.h>

#define CN  64
#define NN  1024
#define HIDN 128

// ---------------------------------------------------------------------------
// Kernel A: prep. For each (h, n):
//   pj[h,n] = sum_c W1[h, c]    * tanh(x[c,n])   (j-side)
//   pi[h,n] = sum_c W1[h, 64+c] * tanh(x[c,n])   (i-side)
//   U = tanh(pi + b1[h]); V = tanh(pj)
//   S[h][n] = (U, W2[h]*U, V, W2[h]*V)
// Grid: 128 blocks x 256 threads, 8 columns n per block.
// ---------------------------------------------------------------------------
__global__ __launch_bounds__(256) void prep_kernel(
    const float* __restrict__ x, const float* __restrict__ W1,
    const float* __restrict__ b1, const float* __restrict__ W2,
    float4* __restrict__ S)
{
    // t_s[nl][c]: stride 68 floats (=272B, 16B-aligned rows; 68%32==4 -> b128
    // reads at distinct nl hit distinct bank groups, conflict-free)
    __shared__ float t_s[8][68];
    const int tid = threadIdx.x;
    const int n0  = blockIdx.x * 8;

    for (int idx = tid; idx < 8 * CN; idx += 256) {
        int nl = idx & 7, c = idx >> 3;
        t_s[nl][c] = tanhf(x[c * NN + n0 + nl]);
    }
    __syncthreads();

    const int nl = tid & 7;
    int h = tid >> 3;
    for (int k = 0; k < 4; ++k, h += 32) {
        const float4* wrow = (const float4*)(W1 + h * (2 * CN));
        float pj = 0.f, pi = 0.f;
#pragma unroll
        for (int c4 = 0; c4 < 16; ++c4) {
            float4 tv = *(const float4*)&t_s[nl][c4 * 4];
            float4 wl = wrow[c4];        // W1[h][4c..4c+3]   (j-side half)
            float4 wh = wrow[16 + c4];   // W1[h][64+4c..]    (i-side half)
            pj = fmaf(wl.x, tv.x, fmaf(wl.y, tv.y, fmaf(wl.z, tv.z, fmaf(wl.w, tv.w, pj))));
            pi = fmaf(wh.x, tv.x, fmaf(wh.y, tv.y, fmaf(wh.z, tv.z, fmaf(wh.w, tv.w, pi))));
        }
        float U  = tanhf(pi + b1[h]);
        float V  = tanhf(pj);
        float w2 = W2[h];
        S[h * NN + n0 + nl] = make_float4(U, w2 * U, V, w2 * V);
    }
}

// ---------------------------------------------------------------------------
// Kernel B: out[i,j] = 2*b2 + sum_h [ (WU_i+WV_j)/(1+U_i V_j)
//                                   + (WU_j+WV_i)/(1+U_j V_i) ]
// Triangular 32x32 tile grid (bi<=bj); each block writes tile and transpose.
// Per-thread 2x2 register block with {+0,+16} lane mapping so LDS float4
// reads are consecutive across lanes (2-way aliasing only == free).
// Paired rcp: one v_rcp serves both symmetric denominators.
// ---------------------------------------------------------------------------
__device__ __forceinline__ void sym_term(const float4& A, const float4& B, float& acc)
{
    // A = (U_i, WU_i, V_i, WV_i) ; B = (U_j, WU_j, V_j, WV_j)
    float d1 = fmaf(A.x, B.z, 1.0f);   // 1 + U_i * V_j
    float d2 = fmaf(B.x, A.z, 1.0f);   // 1 + U_j * V_i
    float n1 = A.y + B.w;              // WU_i + WV_j
    float n2 = B.y + A.w;              // WU_j + WV_i
    float r  = __builtin_amdgcn_rcpf(d1 * d2);
    acc = fmaf(n1, d2 * r, fmaf(n2, d1 * r, acc));
}

__global__ __launch_bounds__(256) void pair_kernel(
    const float4* __restrict__ S, const float* __restrict__ b2,
    float* __restrict__ out)
{
    const int bj = blockIdx.x, bi = blockIdx.y;
    if (bi > bj) return;

    __shared__ float4 Si[32][32];   // [h_local][i_local] 16 KB
    __shared__ float4 Sj[32][32];   // [h_local][j_local] 16 KB

    const int tid = threadIdx.x;
    const int tx = tid & 15, ty = tid >> 4;
    const int i0 = bi * 32, j0 = bj * 32;

    float acc00 = 0.f, acc01 = 0.f, acc10 = 0.f, acc11 = 0.f;

    for (int hc = 0; hc < 4; ++hc) {
        const int h0 = hc * 32;
        __syncthreads();  // prior chunk's reads done before overwrite
#pragma unroll
        for (int k = 0; k < 4; ++k) {
            int t  = tid + k * 256;
            int hl = t >> 5, nl = t & 31;
            Si[hl][nl] = S[(h0 + hl) * NN + i0 + nl];
            Sj[hl][nl] = S[(h0 + hl) * NN + j0 + nl];
        }
        __syncthreads();
#pragma unroll 8
        for (int hl = 0; hl < 32; ++hl) {
            float4 A0 = Si[hl][ty];
            float4 A1 = Si[hl][ty + 16];
            float4 B0 = Sj[hl][tx];
            float4 B1 = Sj[hl][tx + 16];
            sym_term(A0, B0, acc00);
            sym_term(A0, B1, acc01);
            sym_term(A1, B0, acc10);
            sym_term(A1, B1, acc11);
        }
    }

    const float bias2 = 2.0f * b2[0];
    const float v00 = acc00 + bias2, v01 = acc01 + bias2;
    const float v10 = acc10 + bias2, v11 = acc11 + bias2;

    // direct tile (rows i, cols j) — coalesced within 16-lane groups
    out[(i0 + ty)      * NN + j0 + tx]      = v00;
    out[(i0 + ty)      * NN + j0 + tx + 16] = v01;
    out[(i0 + ty + 16) * NN + j0 + tx]      = v10;
    out[(i0 + ty + 16) * NN + j0 + tx + 16] = v11;

    if (bi != bj) {
        // transpose through LDS (reuse Si; 32x33 floats = 4224 B), then
        // coalesced write of tile (bj, bi). Value is symmetric.
        __syncthreads();
        float* T = (float*)&Si[0][0];
        T[ty * 33 + tx]             = v00;
        T[ty * 33 + tx + 16]        = v01;
        T[(ty + 16) * 33 + tx]      = v10;
        T[(ty + 16) * 33 + tx + 16] = v11;
        __syncthreads();
        out[(j0 + ty)      * NN + i0 + tx]      = T[tx * 33 + ty];
        out[(j0 + ty)      * NN + i0 + tx + 16] = T[(tx + 16) * 33 + ty];
        out[(j0 + ty + 16) * NN + i0 + tx]      = T[tx * 33 + ty + 16];
        out[(j0 + ty + 16) * NN + i0 + tx + 16] = T[(tx + 16) * 33 + ty + 16];
    }
}

extern "C" void kernel_launch(void* const* d_in, const int* in_sizes, int n_in,
                              void* d_out, int out_size, void* d_ws, size_t ws_size,
                              hipStream_t stream)
{
    const float* x  = (const float*)d_in[0];   // [1,64,1024]
    const float* W1 = (const float*)d_in[1];   // [128,128]
    const float* b1 = (const float*)d_in[2];   // [128]
    const float* W2 = (const float*)d_in[3];   // [128]
    const float* b2 = (const float*)d_in[4];   // [1]
    float* out = (float*)d_out;                // [1,1024,1024] fp32
    float4* S  = (float4*)d_ws;                // 128*1024*16B = 2 MB scratch

    prep_kernel<<<128, 256, 0, stream>>>(x, W1, b1, W2, S);
    pair_kernel<<<dim3(32, 32), 256, 0, stream>>>(S, b2, out);
}

// Round 2
// 98.914 us; speedup vs baseline: 1.1347x; 1.1347x over previous
//
#include <hip/hip_runtime.h>
#include <math.h>

#define CN   64
#define NN   1024
#define HIDN 128
#define NDIAG 528   // 32*33/2 tiles with bi<=bj
#define NOFF  496   // 31*32/2 tiles with bi<bj

// fast tanh via hardware exp2 + rcp: tanh(x) = 1 - 2/(1+e^{2x})
// large +x: e=inf -> rcp=0 -> 1 ; large -x: e=0 -> -1. ~1e-6 rel err.
__device__ __forceinline__ float tanh_fast(float x) {
    float e = __expf(2.0f * x);
    return 1.0f - 2.0f * __builtin_amdgcn_rcpf(e + 1.0f);
}

// ---------------------------------------------------------------------------
// prep: per (h,n) compute U = tanh(pi+b1[h]), V = tanh(pj); S[h][n]=(U,V).
// 512 blocks x 256 threads; block covers 2 columns n. Thread = (h = tid&127,
// nl = tid>>7) -> nl is wave-uniform so t_s reads broadcast. 4-way split fma
// chains for ILP (old version had 64-deep serial chains, 128 blocks).
// ---------------------------------------------------------------------------
__global__ __launch_bounds__(256) void prep_kernel(
    const float* __restrict__ x, const float* __restrict__ W1,
    const float* __restrict__ b1, float2* __restrict__ S)
{
    __shared__ float t_s[2][64];
    const int tid = threadIdx.x;
    const int n0  = blockIdx.x * 2;

    if (tid < 64) {
        float2 xv = *(const float2*)&x[tid * NN + n0];
        t_s[0][tid] = tanh_fast(xv.x);
        t_s[1][tid] = tanh_fast(xv.y);
    }
    __syncthreads();

    const int h  = tid & 127;
    const int nl = tid >> 7;
    const float4* wrow = (const float4*)(W1 + h * (2 * CN));

    float pj[4] = {0.f, 0.f, 0.f, 0.f};
    float pi[4] = {0.f, 0.f, 0.f, 0.f};
#pragma unroll
    for (int c4 = 0; c4 < 16; ++c4) {
        float4 tv = *(const float4*)&t_s[nl][c4 * 4];
        float4 wl = wrow[c4];        // j-side half W1[h][0..63]
        float4 wh = wrow[16 + c4];   // i-side half W1[h][64..127]
        const int s = c4 & 3;
        pj[s] = fmaf(wl.x, tv.x, fmaf(wl.y, tv.y, fmaf(wl.z, tv.z, fmaf(wl.w, tv.w, pj[s]))));
        pi[s] = fmaf(wh.x, tv.x, fmaf(wh.y, tv.y, fmaf(wh.z, tv.z, fmaf(wh.w, tv.w, pi[s]))));
    }
    float pjs = (pj[0] + pj[1]) + (pj[2] + pj[3]);
    float pis = (pi[0] + pi[1]) + (pi[2] + pi[3]);
    float U = tanh_fast(pis + b1[h]);
    float V = tanh_fast(pjs);
    S[h * NN + n0 + nl] = make_float2(U, V);
}

// ---------------------------------------------------------------------------
// pair: s(i,j) = sum_h W2[h]*[(U_i+V_j)/(1+U_iV_j) + (U_j+V_i)/(1+U_jV_i)]
// W2[h] is block-uniform -> scalar; S fragments are float2 (ds_read_b64).
// Grid 1024 blocks, 1D:
//   id < 528 : triangular tiles (bi<=bj). diag: full h, final value.
//              off-diag: h chunk 0 (h<64), raw partial -> upper tile (i,j).
//   id >= 528: off-diag tiles, h chunk 1 (h>=64), raw partial transposed ->
//              lower tile (j,i).
// combine_kernel later sums the two partials + 2*b2 into both mirror tiles.
// ---------------------------------------------------------------------------
__device__ __forceinline__ void sym_term(float w2h, float2 A, float2 B, float& acc)
{
    // A = (U_i, V_i); B = (U_j, V_j)
    float d1 = fmaf(A.x, B.y, 1.0f);   // 1 + U_i V_j
    float d2 = fmaf(B.x, A.y, 1.0f);   // 1 + U_j V_i
    float n1 = A.x + B.y;              // U_i + V_j
    float n2 = B.x + A.y;              // U_j + V_i
    float r  = __builtin_amdgcn_rcpf(d1 * d2);
    float t  = fmaf(n1, d2, n2 * d1);
    acc = fmaf(w2h, t * r, acc);
}

__global__ __launch_bounds__(256) void pair_kernel(
    const float2* __restrict__ S, const float* __restrict__ W2,
    const float* __restrict__ b2, float* __restrict__ out)
{
    const int id = blockIdx.x;
    int bi, bj, h0, nchunk;
    bool chunk1;
    if (id < NDIAG) {
        int t = id;                                   // t = r(r+1)/2 + c, c<=r
        int r = (int)((sqrtf(8.f * t + 1.f) - 1.f) * 0.5f);
        while ((r + 1) * (r + 2) / 2 <= t) ++r;
        while (r * (r + 1) / 2 > t) --r;
        int c = t - r * (r + 1) / 2;
        bi = c; bj = r; chunk1 = false;
        h0 = 0; nchunk = (bi == bj) ? 4 : 2;
    } else {
        int t = id - NDIAG;                           // t = r(r-1)/2 + c, c<r
        int r = (int)((1.f + sqrtf(8.f * t + 1.f)) * 0.5f);
        while (r * (r - 1) / 2 > t) --r;
        while (r * (r + 1) / 2 <= t) ++r;
        int c = t - r * (r - 1) / 2;
        bi = c; bj = r; chunk1 = true;
        h0 = 64; nchunk = 2;
    }

    __shared__ float2 Si[32][32];   // 8 KB
    __shared__ float2 Sj[32][32];   // 8 KB

    const int tid = threadIdx.x;
    const int tx = tid & 15, ty = tid >> 4;
    const int i0 = bi * 32, j0 = bj * 32;

    float acc00 = 0.f, acc01 = 0.f, acc10 = 0.f, acc11 = 0.f;

    for (int hc = 0; hc < nchunk; ++hc) {
        const int hbase = h0 + hc * 32;
        __syncthreads();
#pragma unroll
        for (int k = 0; k < 4; ++k) {
            int t2 = tid + k * 256;
            int hl = t2 >> 5, nl = t2 & 31;
            Si[hl][nl] = S[(hbase + hl) * NN + i0 + nl];
            Sj[hl][nl] = S[(hbase + hl) * NN + j0 + nl];
        }
        __syncthreads();
#pragma unroll 8
        for (int hl = 0; hl < 32; ++hl) {
            float w2h = W2[hbase + hl];   // uniform -> s_load
            float2 A0 = Si[hl][ty];
            float2 A1 = Si[hl][ty + 16];
            float2 B0 = Sj[hl][tx];
            float2 B1 = Sj[hl][tx + 16];
            sym_term(w2h, A0, B0, acc00);
            sym_term(w2h, A0, B1, acc01);
            sym_term(w2h, A1, B0, acc10);
            sym_term(w2h, A1, B1, acc11);
        }
    }

    if (!chunk1) {
        float v00 = acc00, v01 = acc01, v10 = acc10, v11 = acc11;
        if (bi == bj) {
            const float bias2 = 2.0f * b2[0];
            v00 += bias2; v01 += bias2; v10 += bias2; v11 += bias2;
        }
        out[(i0 + ty)      * NN + j0 + tx]      = v00;
        out[(i0 + ty)      * NN + j0 + tx + 16] = v01;
        out[(i0 + ty + 16) * NN + j0 + tx]      = v10;
        out[(i0 + ty + 16) * NN + j0 + tx + 16] = v11;
    } else {
        // transpose partial through LDS, store at mirror tile (j,i), coalesced
        __syncthreads();
        float* T = (float*)&Si[0][0];   // 32x33 floats fits in 8 KB
        T[ty * 33 + tx]             = acc00;
        T[ty * 33 + tx + 16]        = acc01;
        T[(ty + 16) * 33 + tx]      = acc10;
        T[(ty + 16) * 33 + tx + 16] = acc11;
        __syncthreads();
        out[(j0 + ty)      * NN + i0 + tx]      = T[tx * 33 + ty];
        out[(j0 + ty)      * NN + i0 + tx + 16] = T[(tx + 16) * 33 + ty];
        out[(j0 + ty + 16) * NN + i0 + tx]      = T[tx * 33 + ty + 16];
        out[(j0 + ty + 16) * NN + i0 + tx + 16] = T[(tx + 16) * 33 + ty + 16];
    }
}

// ---------------------------------------------------------------------------
// combine: for each off-diag tile pair, final = p0 + p1 + 2*b2 written to
// both mirror positions. Upper tile holds p0(i,j); lower tile holds p1
// stored so that lower[r][c] = p1(pair(i0+c, j0+r)).
// ---------------------------------------------------------------------------
__global__ __launch_bounds__(256) void combine_kernel(
    const float* __restrict__ b2, float* __restrict__ out)
{
    int t = blockIdx.x;                               // [0,496), c<r
    int r = (int)((1.f + sqrtf(8.f * t + 1.f)) * 0.5f);
    while (r * (r - 1) / 2 > t) --r;
    while (r * (r + 1) / 2 <= t) ++r;
    int c = t - r * (r - 1) / 2;
    const int i0 = c * 32, j0 = r * 32;

    __shared__ float Ua[32][33];
    __shared__ float Lb[32][33];
    const int tid = threadIdx.x;
    const int tx = tid & 15, ty = tid >> 4;

    Ua[ty][tx]           = out[(i0 + ty)      * NN + j0 + tx];
    Ua[ty][tx + 16]      = out[(i0 + ty)      * NN + j0 + tx + 16];
    Ua[ty + 16][tx]      = out[(i0 + ty + 16) * NN + j0 + tx];
    Ua[ty + 16][tx + 16] = out[(i0 + ty + 16) * NN + j0 + tx + 16];
    Lb[ty][tx]           = out[(j0 + ty)      * NN + i0 + tx];
    Lb[ty][tx + 16]      = out[(j0 + ty)      * NN + i0 + tx + 16];
    Lb[ty + 16][tx]      = out[(j0 + ty + 16) * NN + i0 + tx];
    Lb[ty + 16][tx + 16] = out[(j0 + ty + 16) * NN + i0 + tx + 16];
    __syncthreads();

    const float bias2 = 2.0f * b2[0];
    // upper (i0+ry, j0+cx): p0 = Ua[ry][cx], p1 = Lb[cx][ry]
#pragma unroll
    for (int k = 0; k < 4; ++k) {
        int ry = ty + (k >> 1) * 16;
        int cx = tx + (k & 1) * 16;
        out[(i0 + ry) * NN + j0 + cx] = Ua[ry][cx] + Lb[cx][ry] + bias2;
    }
    // lower (j0+ry, i0+cx): pair = (i0+cx, j0+ry): p0 = Ua[cx][ry], p1 = Lb[ry][cx]
#pragma unroll
    for (int k = 0; k < 4; ++k) {
        int ry = ty + (k >> 1) * 16;
        int cx = tx + (k & 1) * 16;
        out[(j0 + ry) * NN + i0 + cx] = Ua[cx][ry] + Lb[ry][cx] + bias2;
    }
}

extern "C" void kernel_launch(void* const* d_in, const int* in_sizes, int n_in,
                              void* d_out, int out_size, void* d_ws, size_t ws_size,
                              hipStream_t stream)
{
    const float* x  = (const float*)d_in[0];   // [1,64,1024]
    const float* W1 = (const float*)d_in[1];   // [128,128]
    const float* b1 = (const float*)d_in[2];   // [128]
    const float* W2 = (const float*)d_in[3];   // [128]
    const float* b2 = (const float*)d_in[4];   // [1]
    float* out = (float*)d_out;                // [1,1024,1024] fp32
    float2* S  = (float2*)d_ws;                // 128*1024*8B = 1 MB scratch

    prep_kernel<<<512, 256, 0, stream>>>(x, W1, b1, S);
    pair_kernel<<<NDIAG + NOFF, 256, 0, stream>>>(S, W2, b2, out);
    combine_kernel<<<NOFF, 256, 0, stream>>>(b2, out);
}